// Round 3
// baseline (1002.292 us; speedup 1.0000x reference)
//
#include <hip/hip_runtime.h>
#include <hip/hip_bf16.h>

#define NN 50000
#define NE 800000
#define DD 256
#define EPSV 1e-5f

typedef float f32x4 __attribute__((ext_vector_type(4)));
typedef short bf16x8s __attribute__((ext_vector_type(8)));
typedef unsigned int uint32;

__device__ __forceinline__ float bf2f(unsigned int u16) {  // low 16 bits = bf16
  unsigned int x = u16 << 16;
  return __builtin_bit_cast(float, x);
}
__device__ __forceinline__ unsigned short f2bf(float f) {
  return __builtin_bit_cast(unsigned short, __float2bfloat16(f));
}

__device__ __forceinline__ void mfma_bf16(bf16x8s a, bf16x8s b, f32x4& c) {
  asm("v_mfma_f32_16x16x32_bf16 %0, %1, %2, %0" : "+v"(c) : "v"(a), "v"(b));
}

__device__ __forceinline__ void gload_lds16(const void* g, void* l) {
  __builtin_amdgcn_global_load_lds((const __attribute__((address_space(1))) void*)g,
                                   (__attribute__((address_space(3))) void*)l, 16, 0, 0);
}

// Chunked activation layout: for chunk c (16 feats), node n:
//   ushort base = (c*NN + n)*32 ; [0..15] = hi bf16 of feats 0..15, [16..31] = lo bf16.

// ---------------- CSR build (by dst) ----------------

__global__ void deg_count_k(const int* __restrict__ ei, int* __restrict__ deg) {
  int e = blockIdx.x * 256 + threadIdx.x;
  if (e < NE) atomicAdd(&deg[ei[NE + e]], 1);
}

__global__ void scan1_k(const int* __restrict__ deg, int* __restrict__ row_ptr,
                        int* __restrict__ blockSums) {
  __shared__ int s[1024];
  int gid = blockIdx.x * 1024 + threadIdx.x;
  int v = (gid < NN) ? deg[gid] : 0;
  s[threadIdx.x] = v;
  __syncthreads();
  for (int off = 1; off < 1024; off <<= 1) {
    int t = (threadIdx.x >= off) ? s[threadIdx.x - off] : 0;
    __syncthreads();
    s[threadIdx.x] += t;
    __syncthreads();
  }
  if (gid < NN) row_ptr[gid] = s[threadIdx.x] - v;
  if (threadIdx.x == 1023) blockSums[blockIdx.x] = s[1023];
}

__global__ void scan2_k(const int* __restrict__ blockSums, int* __restrict__ blockOffs,
                        int* __restrict__ row_ptr, int nblocks) {
  if (threadIdx.x == 0) {
    int run = 0;
    for (int i = 0; i < nblocks; ++i) { blockOffs[i] = run; run += blockSums[i]; }
    row_ptr[NN] = run;
  }
}

__global__ void scan3_k(int* __restrict__ row_ptr, const int* __restrict__ blockOffs,
                        const int* __restrict__ deg, float* __restrict__ deg_inv) {
  int gid = blockIdx.x * 1024 + threadIdx.x;
  if (gid < NN) {
    row_ptr[gid] += blockOffs[blockIdx.x];
    deg_inv[gid] = 1.0f / (float)max(deg[gid], 1);
  }
}

__global__ void csr_fill_k(const int* __restrict__ ei, int* __restrict__ cursor,
                           int* __restrict__ col_idx) {
  int e = blockIdx.x * 256 + threadIdx.x;
  if (e < NE) {
    int pos = atomicAdd(&cursor[ei[NE + e]], 1);
    col_idx[pos] = ei[e];
  }
}

// ---------------- x (row-major f32) -> chunked hi/lo bf16 ----------------

__global__ __launch_bounds__(256) void split_x_k(const float* __restrict__ x,
                                                 uint32* __restrict__ xc) {
  int ni = threadIdx.x & 15, c = threadIdx.x >> 4;
  int node = blockIdx.x * 16 + ni;
  const float4* xr = reinterpret_cast<const float4*>(x + (size_t)node * DD + c * 16);
  float f[16];
#pragma unroll
  for (int q = 0; q < 4; ++q) {
    float4 v = xr[q];
    f[q * 4 + 0] = v.x; f[q * 4 + 1] = v.y; f[q * 4 + 2] = v.z; f[q * 4 + 3] = v.w;
  }
  uint32 wbuf[16];
#pragma unroll
  for (int g = 0; g < 8; ++g) {
    unsigned short h0 = f2bf(f[2 * g]), h1 = f2bf(f[2 * g + 1]);
    unsigned short l0 = f2bf(f[2 * g] - bf2f(h0));
    unsigned short l1 = f2bf(f[2 * g + 1] - bf2f(h1));
    wbuf[g] = (uint32)h0 | ((uint32)h1 << 16);
    wbuf[8 + g] = (uint32)l0 | ((uint32)l1 << 16);
  }
  uint32* dst = xc + ((size_t)c * NN + node) * 16;
#pragma unroll
  for (int q = 0; q < 4; ++q)
    reinterpret_cast<uint4*>(dst)[q] =
        make_uint4(wbuf[q * 4], wbuf[q * 4 + 1], wbuf[q * 4 + 2], wbuf[q * 4 + 3]);
}

// ---------------- W (din x dout) -> W^T hi/lo bf16 planes, all 6 weights ----------------

__global__ __launch_bounds__(256) void wtprep_k(
    const float* __restrict__ W0, const float* __restrict__ W1,
    const float* __restrict__ W2, const float* __restrict__ W3,
    const float* __restrict__ W4, const float* __restrict__ W5,
    unsigned short* __restrict__ wt) {
  int p = blockIdx.y;
  const float* W = (p == 0) ? W0 : (p == 1) ? W1 : (p == 2) ? W2
                   : (p == 3) ? W3 : (p == 4) ? W4 : W5;
  unsigned short* thi = wt + (size_t)(2 * p) * 65536;
  unsigned short* tlo = wt + (size_t)(2 * p + 1) * 65536;
  int gid = blockIdx.x * 256 + threadIdx.x;  // 16384 = 256 n * 64 k-quads
  int n = gid >> 6, k4 = (gid & 63) << 2;
  ushort4 hi, lo;
  unsigned short* hp = &hi.x; unsigned short* lp = &lo.x;
#pragma unroll
  for (int r = 0; r < 4; ++r) {
    float v = W[(size_t)(k4 + r) * DD + n];
    unsigned short h = f2bf(v);
    hp[r] = h;
    lp[r] = f2bf(v - bf2f(h));
  }
  *reinterpret_cast<ushort4*>(thi + (size_t)n * DD + k4) = hi;
  *reinterpret_cast<ushort4*>(tlo + (size_t)n * DD + k4) = lo;
}

// ---------------- chunked aggregation: 16 lanes per node, per chunk ----------------

__global__ __launch_bounds__(256) void sage_agg_k(
    const uint32* __restrict__ act, const int* __restrict__ rp,
    const int* __restrict__ ci, const float* __restrict__ deg_inv,
    uint32* __restrict__ agg) {
  int c = blockIdx.y;
  int node = blockIdx.x * 16 + (threadIdx.x >> 4);
  int gl = threadIdx.x & 15;
  const uint32* base = act + (size_t)c * NN * 16;
  int beg = rp[node], end = rp[node + 1];
  float s0 = 0.f, s1 = 0.f;
  int e = beg;
  for (; e + 4 <= end; e += 4) {
    int n0 = ci[e], n1 = ci[e + 1], n2 = ci[e + 2], n3 = ci[e + 3];
    uint32 u0 = base[(size_t)n0 * 16 + gl];
    uint32 u1 = base[(size_t)n1 * 16 + gl];
    uint32 u2 = base[(size_t)n2 * 16 + gl];
    uint32 u3 = base[(size_t)n3 * 16 + gl];
    s0 += (bf2f(u0 & 0xffff) + bf2f(u1 & 0xffff)) + (bf2f(u2 & 0xffff) + bf2f(u3 & 0xffff));
    s1 += (bf2f(u0 >> 16) + bf2f(u1 >> 16)) + (bf2f(u2 >> 16) + bf2f(u3 >> 16));
  }
  for (; e < end; ++e) {
    uint32 u = base[(size_t)ci[e] * 16 + gl];
    s0 += bf2f(u & 0xffff);
    s1 += bf2f(u >> 16);
  }
  // fold hi-plane partial (lanes 0-7) with lo-plane partial (lanes 8-15)
  float t0 = s0 + __shfl_xor(s0, 8);
  float t1 = s1 + __shfl_xor(s1, 8);
  float di = deg_inv[node];
  t0 *= di; t1 *= di;
  unsigned short h0 = f2bf(t0), h1 = f2bf(t1);
  uint32 word;
  if (gl < 8) {
    word = (uint32)h0 | ((uint32)h1 << 16);
  } else {
    unsigned short l0 = f2bf(t0 - bf2f(h0));
    unsigned short l1 = f2bf(t1 - bf2f(h1));
    word = (uint32)l0 | ((uint32)l1 << 16);
  }
  agg[(size_t)c * NN * 16 + (size_t)node * 16 + gl] = word;
}

// ---------------- MFMA GEMM: 64x256 tile, BK=32, dbuf + 2-phase prefetch ----------------
// A (chunked act) read once; each of 4 waves owns 64 cols x 64 rows.

template <bool DO_BN>
__global__ __launch_bounds__(256) void sage_gemm_k(
    const unsigned short* __restrict__ aggC, const unsigned short* __restrict__ hC,
    const unsigned short* __restrict__ wlHi, const unsigned short* __restrict__ wlLo,
    const unsigned short* __restrict__ wrHi, const unsigned short* __restrict__ wrLo,
    const float* __restrict__ bias,
    const float* __restrict__ gamma, const float* __restrict__ beta,
    const float* __restrict__ mean, const float* __restrict__ var,
    float* __restrict__ outF, unsigned short* __restrict__ outC) {
  __shared__ __attribute__((aligned(128))) char lds[2][40960];  // [A 8KB][B 32KB]

  int tid = threadIdx.x, wave = tid >> 6, lane = tid & 63;
  int lr = lane & 15, lq = lane >> 4;
  int m0 = blockIdx.x * 64;

  f32x4 acc[4][4];
#pragma unroll
  for (int i = 0; i < 4; ++i)
#pragma unroll
    for (int j = 0; j < 4; ++j) acc[i][j] = (f32x4)0.f;

  auto STAGE = [&](char* L, int kt) {
    const unsigned short* act;
    const unsigned short* wh;
    const unsigned short* wl_;
    if (kt < 8) { act = aggC; wh = wlHi; wl_ = wlLo; }
    else        { act = hC;   wh = wrHi; wl_ = wrLo; }
    int kk = (kt & 7) * 32 + lq * 8;   // lane's k-start within the 256-half
    int cch = kk >> 4, ko = kk & 15;   // chunk, offset-in-chunk (0 or 8)
#pragma unroll
    for (int t = 0; t < 10; ++t) {
      int u = wave * 10 + t;           // 40 staging units of 1KB
      if (u < 8) {                     // A: mi = u>>1, plane = u&1
        int mi = u >> 1, pl = u & 1;
        int gm = m0 + mi * 16 + lr;
        gm = gm < NN ? gm : NN - 1;
        gload_lds16(act + (size_t)(cch * NN + gm) * 32 + pl * 16 + ko,
                    L + u * 1024 + lane * 16);
      } else {                         // B: v = u-8, ni = v>>1, plane = v&1
        int v = u - 8, ni = v >> 1, pl = v & 1;
        const unsigned short* w = pl ? wl_ : wh;
        gload_lds16(w + (size_t)(ni * 16 + lr) * DD + kk,
                    L + 8192 + v * 1024 + lane * 16);
      }
    }
  };

  auto COMPUTE = [&](const char* L) {
    bf16x8s fbhi[4], fblo[4];
#pragma unroll
    for (int j = 0; j < 4; ++j) {
      int ni = wave * 4 + j;
      fbhi[j] = *reinterpret_cast<const bf16x8s*>(L + 8192 + ni * 2048 + lane * 16);
      fblo[j] = *reinterpret_cast<const bf16x8s*>(L + 8192 + ni * 2048 + 1024 + lane * 16);
    }
#pragma unroll
    for (int i = 0; i < 4; ++i) {
      bf16x8s fahi = *reinterpret_cast<const bf16x8s*>(L + i * 2048 + lane * 16);
      bf16x8s falo = *reinterpret_cast<const bf16x8s*>(L + i * 2048 + 1024 + lane * 16);
#pragma unroll
      for (int j = 0; j < 4; ++j) {
        mfma_bf16(fahi, fbhi[j], acc[i][j]);
        mfma_bf16(fahi, fblo[j], acc[i][j]);
        mfma_bf16(falo, fbhi[j], acc[i][j]);
      }
    }
  };

  STAGE(lds[0], 0);
  __syncthreads();                    // compiler emits vmcnt(0) drain + barrier
  int cur = 0;
#pragma unroll 1
  for (int kt = 0; kt < 15; ++kt) {
    STAGE(lds[cur ^ 1], kt + 1);      // loads in flight under the MFMAs below
    COMPUTE(lds[cur]);
    __syncthreads();
    cur ^= 1;
  }
  COMPUTE(lds[cur]);

  // ---- epilogue ----
#pragma unroll
  for (int j = 0; j < 4; ++j) {
    int n = wave * 64 + j * 16 + lr;
    float bb = bias[n], sc = 0.f, sh = 0.f;
    if (DO_BN) {
      float s = gamma[n] * rsqrtf(var[n] + EPSV);
      sc = s;
      sh = beta[n] - mean[n] * s;
    }
    int cch = n >> 4, o = n & 15;
#pragma unroll
    for (int i = 0; i < 4; ++i) {
#pragma unroll
      for (int r = 0; r < 4; ++r) {
        int m = m0 + i * 16 + lq * 4 + r;
        if (m < NN) {
          float v = acc[i][j][r] + bb;
          if (DO_BN) {
            v = fmaxf(v * sc + sh, 0.f);
            size_t ub = (size_t)(cch * NN + m) * 32;
            v += bf2f(hC[ub + o]) + bf2f(hC[ub + 16 + o]);  // residual reconstruct
            unsigned short h = f2bf(v);
            outC[ub + o] = h;
            outC[ub + 16 + o] = f2bf(v - bf2f(h));
          } else {
            outF[(size_t)m * DD + n] = v;
          }
        }
      }
    }
  }
}

// ---------------- launch ----------------

extern "C" void kernel_launch(void* const* d_in, const int* in_sizes, int n_in,
                              void* d_out, int out_size, void* d_ws, size_t ws_size,
                              hipStream_t stream) {
  const float* x   = (const float*)d_in[0];
  const int*   ei  = (const int*)d_in[1];
  const float* Wl[3] = {(const float*)d_in[2], (const float*)d_in[5], (const float*)d_in[8]};
  const float* Wr[3] = {(const float*)d_in[3], (const float*)d_in[6], (const float*)d_in[9]};
  const float* bs[3] = {(const float*)d_in[4], (const float*)d_in[7], (const float*)d_in[10]};
  const float* g0  = (const float*)d_in[11];
  const float* be0 = (const float*)d_in[12];
  const float* mu0 = (const float*)d_in[13];
  const float* va0 = (const float*)d_in[14];
  const float* g1  = (const float*)d_in[15];
  const float* be1 = (const float*)d_in[16];
  const float* mu1 = (const float*)d_in[17];
  const float* va1 = (const float*)d_in[18];
  float* out = (float*)d_out;

  char* w = (char*)d_ws;
  const size_t o_deg    = 0;
  const size_t o_rowptr = 262144;
  const size_t o_cursor = 524288;
  const size_t o_colidx = 786432;
  const size_t o_deginv = 4194304;
  const size_t o_bsum   = 4456448;
  const size_t o_boff   = 4460544;
  const size_t o_wt     = 4464640;                 // 12 planes * 131072 B
  const size_t ACT      = (size_t)16 * NN * 64;    // 51.2 MB chunked buffer
  const size_t o_xC     = 6291456;
  const size_t o_h1C    = o_xC + ACT;
  const size_t o_aggC   = o_xC + 2 * ACT;          // end ~159.9 MB

  int*   deg     = (int*)(w + o_deg);
  int*   row_ptr = (int*)(w + o_rowptr);
  int*   cursor  = (int*)(w + o_cursor);
  int*   col_idx = (int*)(w + o_colidx);
  float* deg_inv = (float*)(w + o_deginv);
  int*   bsum    = (int*)(w + o_bsum);
  int*   boff    = (int*)(w + o_boff);
  unsigned short* wt   = (unsigned short*)(w + o_wt);
  uint32* xC   = (uint32*)(w + o_xC);
  uint32* h1C  = (uint32*)(w + o_h1C);
  uint32* aggC = (uint32*)(w + o_aggC);

  unsigned short* wlT[3][2];
  unsigned short* wrT[3][2];
  for (int l = 0; l < 3; ++l) {
    wlT[l][0] = wt + (size_t)(4 * l + 0) * 65536;
    wlT[l][1] = wt + (size_t)(4 * l + 1) * 65536;
    wrT[l][0] = wt + (size_t)(4 * l + 2) * 65536;
    wrT[l][1] = wt + (size_t)(4 * l + 3) * 65536;
  }

  const int SCAN_BLOCKS = (NN + 1023) / 1024;  // 49

  // ---- CSR build ----
  hipMemsetAsync(deg, 0, NN * sizeof(int), stream);
  deg_count_k<<<NE / 256, 256, 0, stream>>>(ei, deg);
  scan1_k<<<SCAN_BLOCKS, 1024, 0, stream>>>(deg, row_ptr, bsum);
  scan2_k<<<1, 64, 0, stream>>>(bsum, boff, row_ptr, SCAN_BLOCKS);
  scan3_k<<<SCAN_BLOCKS, 1024, 0, stream>>>(row_ptr, boff, deg, deg_inv);
  hipMemcpyAsync(cursor, row_ptr, NN * sizeof(int), hipMemcpyDeviceToDevice, stream);
  csr_fill_k<<<NE / 256, 256, 0, stream>>>(ei, cursor, col_idx);

  // ---- precompute chunked x and W^T planes ----
  split_x_k<<<NN / 16, 256, 0, stream>>>(x, xC);
  wtprep_k<<<dim3(64, 6), 256, 0, stream>>>(Wl[0], Wr[0], Wl[1], Wr[1], Wl[2], Wr[2], wt);

  dim3 agrid(NN / 16, 16);        // 3125 node-groups x 16 chunks
  dim3 ggrid((NN + 63) / 64);     // 782

  // ---- layer 0: x -> h1 ----
  sage_agg_k<<<agrid, 256, 0, stream>>>(xC, row_ptr, col_idx, deg_inv, aggC);
  sage_gemm_k<true><<<ggrid, 256, 0, stream>>>(
      (const unsigned short*)aggC, (const unsigned short*)xC,
      wlT[0][0], wlT[0][1], wrT[0][0], wrT[0][1],
      bs[0], g0, be0, mu0, va0, nullptr, (unsigned short*)h1C);
  // ---- layer 1: h1 -> h2 (into xC) ----
  sage_agg_k<<<agrid, 256, 0, stream>>>(h1C, row_ptr, col_idx, deg_inv, aggC);
  sage_gemm_k<true><<<ggrid, 256, 0, stream>>>(
      (const unsigned short*)aggC, (const unsigned short*)h1C,
      wlT[1][0], wlT[1][1], wrT[1][0], wrT[1][1],
      bs[1], g1, be1, mu1, va1, nullptr, (unsigned short*)xC);
  // ---- layer 2: h2 -> out (fp32) ----
  sage_agg_k<<<agrid, 256, 0, stream>>>(xC, row_ptr, col_idx, deg_inv, aggC);
  sage_gemm_k<false><<<ggrid, 256, 0, stream>>>(
      (const unsigned short*)aggC, (const unsigned short*)xC,
      wlT[2][0], wlT[2][1], wrT[2][0], wrT[2][1],
      bs[2], nullptr, nullptr, nullptr, nullptr, out, nullptr);
}